// Round 3
// baseline (2107.357 us; speedup 1.0000x reference)
//
#include <hip/hip_runtime.h>
#include <math.h>

#define N_RN 100000
#define N_ED 1200000
#define N_G  4096
#define SCAN_CH 256
#define SCAN_NB ((N_RN + SCAN_CH - 1) / SCAN_CH)   // 391

__device__ __forceinline__ float lrelu(float x) { return x > 0.f ? x : 0.1f * x; }

// h = r_node @ W_r (wave/node, lane=col, row via coalesced LDS); fused hs/hd layer0
__global__ void k_embed_h(const float* __restrict__ r_node,
                          const float* __restrict__ W_r,
                          const float* __restrict__ a_s0,
                          const float* __restrict__ a_d0,
                          float* __restrict__ h,
                          float* __restrict__ hs, float* __restrict__ hd) {
    __shared__ float Wl[64 * 64];
    __shared__ float arow[4][64];
    int tid = threadIdx.x;
    for (int i = tid; i < 4096; i += 256) Wl[i] = W_r[i];
    __syncthreads();
    int lane = tid & 63, w = tid >> 6;
    float asj = a_s0[lane], adj = a_d0[lane];
    int wid = blockIdx.x * 4 + w;
    int nw = gridDim.x * 4;
    for (int n = wid; n < N_RN; n += nw) {
        arow[w][lane] = r_node[(size_t)n * 64 + lane];
        float acc = 0.f;
#pragma unroll
        for (int d4 = 0; d4 < 16; ++d4) {
            float4 a = *(const float4*)&arow[w][d4 * 4];
            int d = d4 * 4;
            acc += a.x * Wl[(d + 0) * 64 + lane];
            acc += a.y * Wl[(d + 1) * 64 + lane];
            acc += a.z * Wl[(d + 2) * 64 + lane];
            acc += a.w * Wl[(d + 3) * 64 + lane];
        }
        h[(size_t)n * 64 + lane] = acc;
        float x = acc * asj, y = acc * adj;
#pragma unroll
        for (int off = 32; off; off >>= 1) {
            x += __shfl_xor(x, off, 64);
            y += __shfl_xor(y, off, 64);
        }
        if (lane == 0) { hs[n] = x; hd[n] = y; }
    }
}

// ---- CSR build ----
__global__ void k_hist(const int* __restrict__ dst, int* __restrict__ deg) {
    int k = blockIdx.x * blockDim.x + threadIdx.x;
    if (k < N_ED) atomicAdd(deg + dst[k], 1);
}

// per-chunk sums of deg
__global__ void k_scan_a(const int* __restrict__ deg, int* __restrict__ bsum) {
    __shared__ int lds[SCAN_CH];
    int b = blockIdx.x, t = threadIdx.x;
    int i = b * SCAN_CH + t;
    int v = (i < N_RN) ? deg[i] : 0;
    lds[t] = v;
    __syncthreads();
    for (int d = 128; d; d >>= 1) {
        if (t < d) lds[t] += lds[t + d];
        __syncthreads();
    }
    if (t == 0) bsum[b] = lds[0];
}

// exclusive scan of bsum (one block, 512 threads >= SCAN_NB)
__global__ void k_scan_b(int* __restrict__ bsum) {
    __shared__ int lds[512];
    int t = threadIdx.x;
    int v = (t < SCAN_NB) ? bsum[t] : 0;
    lds[t] = v;
    __syncthreads();
    for (int d = 1; d < 512; d <<= 1) {
        int u = (t >= d) ? lds[t - d] : 0;
        __syncthreads();
        lds[t] += u;
        __syncthreads();
    }
    if (t < SCAN_NB) bsum[t] = lds[t] - v;  // exclusive
}

// per-chunk inclusive scan + block offset -> off[], cur[]
__global__ void k_scan_c(const int* __restrict__ deg, const int* __restrict__ bsum,
                         int* __restrict__ off, int* __restrict__ cur) {
    __shared__ int lds[SCAN_CH];
    int b = blockIdx.x, t = threadIdx.x;
    int i = b * SCAN_CH + t;
    int v = (i < N_RN) ? deg[i] : 0;
    lds[t] = v;
    __syncthreads();
    for (int d = 1; d < SCAN_CH; d <<= 1) {
        int u = (t >= d) ? lds[t - d] : 0;
        __syncthreads();
        lds[t] += u;
        __syncthreads();
    }
    if (i < N_RN) {
        int incl = bsum[b] + lds[t];
        off[i + 1] = incl;
        cur[i] = incl - v;
        if (i == 0) off[0] = 0;
    }
}

// scatter edges into dst-sorted order; computes el[0..3] inline (el = r_edge . (W_e@a_e[l]))
__global__ void k_scatter(const float* __restrict__ r_edge,
                          const float* __restrict__ W_e,
                          const float* __restrict__ a_e,
                          const int* __restrict__ src, const int* __restrict__ dst,
                          int* __restrict__ cur,
                          int* __restrict__ src_perm, int* __restrict__ eorig,
                          float* __restrict__ el_perm) {
    __shared__ float wa[4][16];
    int tid = threadIdx.x;
    if (tid < 64) {
        int l = tid >> 4, t = tid & 15;
        float acc = 0.f;
        for (int j = 0; j < 64; ++j) acc += W_e[t * 64 + j] * a_e[l * 64 + j];
        wa[l][t] = acc;
    }
    __syncthreads();
    int k = blockIdx.x * blockDim.x + tid;
    if (k >= N_ED) return;
    const float4* row = (const float4*)(r_edge + (size_t)k * 16);
    float4 r0 = row[0], r1 = row[1], r2 = row[2], r3 = row[3];
    int pos = atomicAdd(cur + dst[k], 1);
    src_perm[pos] = src[k];
    eorig[pos] = k;
#pragma unroll
    for (int l = 0; l < 4; ++l) {
        float acc = r0.x * wa[l][0] + r0.y * wa[l][1] + r0.z * wa[l][2] + r0.w * wa[l][3]
                  + r1.x * wa[l][4] + r1.y * wa[l][5] + r1.z * wa[l][6] + r1.w * wa[l][7]
                  + r2.x * wa[l][8] + r2.y * wa[l][9] + r2.z * wa[l][10] + r2.w * wa[l][11]
                  + r3.x * wa[l][12] + r3.y * wa[l][13] + r3.z * wa[l][14] + r3.w * wa[l][15];
        el_perm[(size_t)l * N_ED + pos] = acc;
    }
}

// fused per-layer conv: wave per node, online softmax over in-edges, msg accum in regs,
// Wm multiply + residual + lrelu + next-layer hs/hd. No atomics. h double-buffered.
__global__ void k_layer(const float* __restrict__ h_in,
                        const float* __restrict__ hs, const float* __restrict__ hd,
                        const int* __restrict__ off,
                        const int* __restrict__ src_perm, const int* __restrict__ eorig,
                        const float* __restrict__ el_l,
                        const float* __restrict__ r_edge,
                        const float* __restrict__ W_e,
                        const float* __restrict__ Wm_l,
                        const float* __restrict__ a_s_n, const float* __restrict__ a_d_n,
                        float* __restrict__ h_out,
                        float* __restrict__ hs_out, float* __restrict__ hd_out) {
    __shared__ float Wl[64 * 64];
    __shared__ float arow[4][64];
    int tid = threadIdx.x;
    for (int i = tid; i < 4096; i += 256) Wl[i] = Wm_l[i];
    __syncthreads();
    int lane = tid & 63, w = tid >> 6;
    float wecol[16];
#pragma unroll
    for (int t = 0; t < 16; ++t) wecol[t] = W_e[t * 64 + lane];
    float asj = a_s_n[lane], adj = a_d_n[lane];
    int wid = blockIdx.x * 4 + w;
    int nw = gridDim.x * 4;
    for (int n = wid; n < N_RN; n += nw) {
        int base = off[n], end = off[n + 1];
        float hdn = hd[n];
        float m = -1e38f, s = 0.f, acc = 0.f;
        for (int c = base; c < end; c += 64) {
            int cnt = min(64, end - c);
            float lg = -1e38f;
            int sk = 0, eo = 0;
            if (lane < cnt) {
                sk = src_perm[c + lane];
                eo = eorig[c + lane];
                lg = lrelu(hs[sk] + hdn + el_l[c + lane]);
            }
            // chunk max
            float cm = lg;
#pragma unroll
            for (int o = 32; o; o >>= 1) cm = fmaxf(cm, __shfl_xor(cm, o, 64));
            float newm = fmaxf(m, cm);
            float scale = (m > -1e37f) ? __expf(m - newm) : 0.f;
            s *= scale;
            acc *= scale;
            m = newm;
            for (int j = 0; j < cnt; ++j) {
                float lgj = __shfl(lg, j, 64);
                int skj = __shfl(sk, j, 64);
                int eoj = __shfl(eo, j, 64);
                float wgt = __expf(lgj - m);
                s += wgt;
                float ev = r_edge[(size_t)eoj * 16 + (lane & 15)];
                float e = 0.f;
#pragma unroll
                for (int t = 0; t < 16; ++t) e += __shfl(ev, t, 64) * wecol[t];
                float hv = h_in[(size_t)skj * 64 + lane];
                acc += wgt * (hv + e);
            }
        }
        float aggv = (end > base) ? acc / s : 0.f;
        // agg @ Wm via LDS row stage
        arow[w][lane] = aggv;
        float mm = 0.f;
#pragma unroll
        for (int d4 = 0; d4 < 16; ++d4) {
            float4 a = *(const float4*)&arow[w][d4 * 4];
            int d = d4 * 4;
            mm += a.x * Wl[(d + 0) * 64 + lane];
            mm += a.y * Wl[(d + 1) * 64 + lane];
            mm += a.z * Wl[(d + 2) * 64 + lane];
            mm += a.w * Wl[(d + 3) * 64 + lane];
        }
        size_t idx = (size_t)n * 64 + lane;
        float hv = lrelu(h_in[idx] + mm);
        h_out[idx] = hv;
        float x = hv * asj, y = hv * adj;
#pragma unroll
        for (int o = 32; o; o >>= 1) {
            x += __shfl_xor(x, o, 64);
            y += __shfl_xor(y, o, 64);
        }
        if (lane == 0) { hs_out[n] = x; hd_out[n] = y; }
    }
}

// block per graph readout (graph_id sorted -> contiguous ranges via binary search)
__global__ void k_readout(const float* __restrict__ h,
                          const float* __restrict__ d_edge,
                          const int* __restrict__ graph_id,
                          const float* __restrict__ i_node,
                          const float* __restrict__ W_i,
                          const float* __restrict__ w_d,
                          const float* __restrict__ b_d,
                          const float* __restrict__ W_mlp,
                          const float* __restrict__ b_mlp,
                          const float* __restrict__ W_out,
                          const float* __restrict__ b_out,
                          float* __restrict__ out) {
    int g = blockIdx.x, j = threadIdx.x;
    int lo = 0, hi = N_RN;
    while (lo < hi) { int mid = (lo + hi) >> 1; if (graph_id[mid] < g) lo = mid + 1; else hi = mid; }
    int start = lo;
    hi = N_RN;
    while (lo < hi) { int mid = (lo + hi) >> 1; if (graph_id[mid] < g + 1) lo = mid + 1; else hi = mid; }
    int end = lo;

    float wd = w_d[0], bd = b_d[0];
    float acc0 = 0.f, acc1 = 0.f, sg = 0.f;
    for (int n = start; n < end; ++n) {
        float hv = h[(size_t)n * 64 + j];
        float de = d_edge[n];
        float gate = 1.f / (1.f + __expf(-(de * wd + bd)));
        acc0 += hv;
        acc1 += gate * hv;
        sg += gate;
    }
    float hij = i_node[g] * W_i[j] + acc1;
    float pooled = acc0 + sg * hij;

    __shared__ float xa[64], xb[64];
    xa[j] = pooled;
    __syncthreads();
#pragma unroll
    for (int layer = 0; layer < 3; ++layer) {
        const float* W = W_mlp + layer * 4096;
        float* srcb = (layer & 1) ? xb : xa;
        float* dstb = (layer & 1) ? xa : xb;
        float acc = b_mlp[layer * 64 + j];
        for (int d = 0; d < 64; ++d) acc += srcb[d] * W[d * 64 + j];
        acc = fmaxf(acc, 0.f);
        __syncthreads();
        dstb[j] = acc;
        __syncthreads();
    }
    float v = xb[j] * W_out[j];
#pragma unroll
    for (int off = 32; off; off >>= 1) v += __shfl_xor(v, off, 64);
    if (j == 0) out[g] = v + b_out[0];
}

extern "C" void kernel_launch(void* const* d_in, const int* in_sizes, int n_in,
                              void* d_out, int out_size, void* d_ws, size_t ws_size,
                              hipStream_t stream) {
    const float* r_node  = (const float*)d_in[0];
    const float* i_node  = (const float*)d_in[1];
    const float* r_edge  = (const float*)d_in[2];
    const float* d_edge  = (const float*)d_in[3];
    const int*   r2r_src = (const int*)d_in[4];
    const int*   r2r_dst = (const int*)d_in[5];
    const int*   graph_id= (const int*)d_in[6];
    const float* W_r     = (const float*)d_in[7];
    const float* W_i     = (const float*)d_in[8];
    const float* W_e     = (const float*)d_in[9];
    const float* Wm      = (const float*)d_in[10];
    const float* a_s     = (const float*)d_in[11];
    const float* a_d     = (const float*)d_in[12];
    const float* a_e     = (const float*)d_in[13];
    const float* w_d     = (const float*)d_in[14];
    const float* b_d     = (const float*)d_in[15];
    const float* W_mlp   = (const float*)d_in[16];
    const float* b_mlp   = (const float*)d_in[17];
    const float* W_out   = (const float*)d_in[18];
    const float* b_out   = (const float*)d_in[19];
    float* out = (float*)d_out;

    float* ws = (float*)d_ws;
    float* h0   = ws;                                  // N*64
    float* h1   = h0 + (size_t)N_RN * 64;              // N*64
    float* hs0  = h1 + (size_t)N_RN * 64;              // N
    float* hd0  = hs0 + N_RN;                          // N
    float* hs1  = hd0 + N_RN;                          // N
    float* hd1  = hs1 + N_RN;                          // N
    int*   deg  = (int*)(hd1 + N_RN);                  // N
    int*   offs = deg + N_RN;                          // N+1
    int*   cur  = offs + N_RN + 1;                     // N
    int*   bsum = cur + N_RN;                          // SCAN_NB
    int*   src_perm = bsum + 512;                      // E
    int*   eorig    = src_perm + N_ED;                 // E
    float* el_perm  = (float*)(eorig + N_ED);          // 4*E

    // embed + layer-0 hs/hd
    k_embed_h<<<2048, 256, 0, stream>>>(r_node, W_r, a_s, a_d, h0, hs0, hd0);

    // CSR build
    hipMemsetAsync(deg, 0, N_RN * sizeof(int), stream);
    k_hist<<<(N_ED + 255) / 256, 256, 0, stream>>>(r2r_dst, deg);
    k_scan_a<<<SCAN_NB, SCAN_CH, 0, stream>>>(deg, bsum);
    k_scan_b<<<1, 512, 0, stream>>>(bsum);
    k_scan_c<<<SCAN_NB, SCAN_CH, 0, stream>>>(deg, bsum, offs, cur);
    k_scatter<<<(N_ED + 255) / 256, 256, 0, stream>>>(r_edge, W_e, a_e, r2r_src, r2r_dst,
                                                      cur, src_perm, eorig, el_perm);

    float* hin = h0;  float* hout = h1;
    float* hsi = hs0; float* hdi = hd0;
    float* hso = hs1; float* hdo = hd1;
    for (int l = 0; l < 4; ++l) {
        int ln = (l + 1) & 3;
        k_layer<<<2048, 256, 0, stream>>>(hin, hsi, hdi, offs, src_perm, eorig,
                                          el_perm + (size_t)l * N_ED, r_edge, W_e,
                                          Wm + l * 4096, a_s + ln * 64, a_d + ln * 64,
                                          hout, hso, hdo);
        float* t;
        t = hin; hin = hout; hout = t;
        t = hsi; hsi = hso; hso = t;
        t = hdi; hdi = hdo; hdo = t;
    }

    k_readout<<<N_G, 64, 0, stream>>>(hin, d_edge, graph_id, i_node, W_i, w_d, b_d,
                                      W_mlp, b_mlp, W_out, b_out, out);
}

// Round 4
// 958.419 us; speedup vs baseline: 2.1988x; 2.1988x over previous
//
#include <hip/hip_runtime.h>
#include <math.h>

#define N_RN 100000
#define N_ED 1200000
#define N_G  4096
#define SCAN_CH 256
#define SCAN_NB ((N_RN + SCAN_CH - 1) / SCAN_CH)   // 391

__device__ __forceinline__ float lrelu(float x) { return x > 0.f ? x : 0.1f * x; }

// h = r_node @ W_r (wave/node, lane=col, row via coalesced LDS); fused hs/hd layer0
__global__ void k_embed_h(const float* __restrict__ r_node,
                          const float* __restrict__ W_r,
                          const float* __restrict__ a_s0,
                          const float* __restrict__ a_d0,
                          float* __restrict__ h,
                          float* __restrict__ hs, float* __restrict__ hd) {
    __shared__ float Wl[64 * 64];
    __shared__ float arow[4][64];
    int tid = threadIdx.x;
    for (int i = tid; i < 4096; i += 256) Wl[i] = W_r[i];
    __syncthreads();
    int lane = tid & 63, w = tid >> 6;
    float asj = a_s0[lane], adj = a_d0[lane];
    int wid = blockIdx.x * 4 + w;
    int nw = gridDim.x * 4;
    for (int n = wid; n < N_RN; n += nw) {
        arow[w][lane] = r_node[(size_t)n * 64 + lane];
        float acc = 0.f;
#pragma unroll
        for (int d4 = 0; d4 < 16; ++d4) {
            float4 a = *(const float4*)&arow[w][d4 * 4];
            int d = d4 * 4;
            acc += a.x * Wl[(d + 0) * 64 + lane];
            acc += a.y * Wl[(d + 1) * 64 + lane];
            acc += a.z * Wl[(d + 2) * 64 + lane];
            acc += a.w * Wl[(d + 3) * 64 + lane];
        }
        h[(size_t)n * 64 + lane] = acc;
        float x = acc * asj, y = acc * adj;
#pragma unroll
        for (int off = 32; off; off >>= 1) {
            x += __shfl_xor(x, off, 64);
            y += __shfl_xor(y, off, 64);
        }
        if (lane == 0) { hs[n] = x; hd[n] = y; }
    }
}

// WeWm[l] = W_e @ Wm[l]  (16x64 per layer)
__global__ void k_wewm(const float* __restrict__ W_e,
                       const float* __restrict__ Wm,
                       float* __restrict__ WeWm) {
    int idx = blockIdx.x * blockDim.x + threadIdx.x;   // 4096 total
    int l = idx >> 10, rem = idx & 1023;
    int t = rem >> 6, j = rem & 63;
    float acc = 0.f;
    for (int d = 0; d < 64; ++d)
        acc += W_e[t * 64 + d] * Wm[l * 4096 + d * 64 + j];
    WeWm[idx] = acc;
}

// ---- CSR build ----
__global__ void k_hist(const int* __restrict__ dst, int* __restrict__ deg) {
    int k = blockIdx.x * blockDim.x + threadIdx.x;
    if (k < N_ED) atomicAdd(deg + dst[k], 1);
}

__global__ void k_scan_a(const int* __restrict__ deg, int* __restrict__ bsum) {
    __shared__ int lds[SCAN_CH];
    int b = blockIdx.x, t = threadIdx.x;
    int i = b * SCAN_CH + t;
    int v = (i < N_RN) ? deg[i] : 0;
    lds[t] = v;
    __syncthreads();
    for (int d = 128; d; d >>= 1) {
        if (t < d) lds[t] += lds[t + d];
        __syncthreads();
    }
    if (t == 0) bsum[b] = lds[0];
}

__global__ void k_scan_b(int* __restrict__ bsum) {
    __shared__ int lds[512];
    int t = threadIdx.x;
    int v = (t < SCAN_NB) ? bsum[t] : 0;
    lds[t] = v;
    __syncthreads();
    for (int d = 1; d < 512; d <<= 1) {
        int u = (t >= d) ? lds[t - d] : 0;
        __syncthreads();
        lds[t] += u;
        __syncthreads();
    }
    if (t < SCAN_NB) bsum[t] = lds[t] - v;  // exclusive
}

__global__ void k_scan_c(const int* __restrict__ deg, const int* __restrict__ bsum,
                         int* __restrict__ off, int* __restrict__ cur) {
    __shared__ int lds[SCAN_CH];
    int b = blockIdx.x, t = threadIdx.x;
    int i = b * SCAN_CH + t;
    int v = (i < N_RN) ? deg[i] : 0;
    lds[t] = v;
    __syncthreads();
    for (int d = 1; d < SCAN_CH; d <<= 1) {
        int u = (t >= d) ? lds[t - d] : 0;
        __syncthreads();
        lds[t] += u;
        __syncthreads();
    }
    if (i < N_RN) {
        int incl = bsum[b] + lds[t];
        off[i + 1] = incl;
        cur[i] = incl - v;
        if (i == 0) off[0] = 0;
    }
}

// scatter edges into dst-sorted order: src_perm + raw 16-float edge row (r16_perm)
__global__ void k_scatter(const float* __restrict__ r_edge,
                          const int* __restrict__ src, const int* __restrict__ dst,
                          int* __restrict__ cur,
                          int* __restrict__ src_perm,
                          float* __restrict__ r16_perm) {
    int k = blockIdx.x * blockDim.x + threadIdx.x;
    if (k >= N_ED) return;
    const float4* row = (const float4*)(r_edge + (size_t)k * 16);
    float4 r0 = row[0], r1 = row[1], r2 = row[2], r3 = row[3];
    int pos = atomicAdd(cur + dst[k], 1);
    src_perm[pos] = src[k];
    float4* o = (float4*)(r16_perm + (size_t)pos * 16);
    o[0] = r0; o[1] = r1; o[2] = r2; o[3] = r3;
}

// fused per-layer conv: wave per node, 4 x 16-lane groups (group = edge, lane = 4 feats).
// online softmax; e-term factored: agg@Wm = hsum@Wm + r16sum@(We@Wm). No atomics.
__global__ void k_layer(const float* __restrict__ h_in,
                        const float* __restrict__ hs, const float* __restrict__ hd,
                        const int* __restrict__ off,
                        const int* __restrict__ src_perm,
                        const float* __restrict__ r16_perm,
                        const float* __restrict__ W_e,
                        const float* __restrict__ a_e_l,
                        const float* __restrict__ Wm_l,
                        const float* __restrict__ WeWm_l,
                        const float* __restrict__ a_s_n, const float* __restrict__ a_d_n,
                        float* __restrict__ h_out,
                        float* __restrict__ hs_out, float* __restrict__ hd_out) {
    __shared__ float Wl[64 * 64];
    __shared__ float Ww[16 * 64];
    __shared__ float was[16];
    __shared__ float arow[4][64];
    __shared__ float rrow[4][16];
    int tid = threadIdx.x;
    for (int i = tid; i < 4096; i += 256) Wl[i] = Wm_l[i];
    for (int i = tid; i < 1024; i += 256) Ww[i] = WeWm_l[i];
    if (tid < 16) {
        float acc = 0.f;
        for (int j = 0; j < 64; ++j) acc += W_e[tid * 64 + j] * a_e_l[j];
        was[tid] = acc;
    }
    __syncthreads();
    int lane = tid & 63, w = tid >> 6;
    int g = lane >> 4, lg = lane & 15;
    float wav = was[lg];
    float asj = a_s_n[lane], adj = a_d_n[lane];
    int wid = blockIdx.x * 4 + w;
    int nw = gridDim.x * 4;
    for (int n = wid; n < N_RN; n += nw) {
        int base = off[n], end = off[n + 1];
        float hdn = hd[n];
        float m = -1e38f, s = 0.f, racc = 0.f;
        float acc0 = 0.f, acc1 = 0.f, acc2 = 0.f, acc3 = 0.f;
        for (int c = base; c < end; c += 4) {
            int pos = c + g;
            bool act = pos < end;
            float rv = 0.f;
            int sk = 0;
            if (act) {
                sk = src_perm[pos];
                rv = r16_perm[(size_t)pos * 16 + lg];
            }
            // edge logit: el = r16 . wa  (4-shfl group reduce; all 16 lanes get it)
            float ep = rv * wav;
            ep += __shfl_xor(ep, 1, 64);
            ep += __shfl_xor(ep, 2, 64);
            ep += __shfl_xor(ep, 4, 64);
            ep += __shfl_xor(ep, 8, 64);
            float lgt = act ? lrelu(hs[sk] + hdn + ep) : -1e38f;
            // max over the 4 groups
            float cm = fmaxf(lgt, __shfl_xor(lgt, 16, 64));
            cm = fmaxf(cm, __shfl_xor(cm, 32, 64));
            float newm = fmaxf(m, cm);
            float scale = (m > -1e37f) ? __expf(m - newm) : 0.f;
            s *= scale; racc *= scale;
            acc0 *= scale; acc1 *= scale; acc2 *= scale; acc3 *= scale;
            m = newm;
            if (act) {
                float wgt = __expf(lgt - m);
                s += wgt;
                const float4 hv = *(const float4*)(h_in + (size_t)sk * 64 + (lg << 2));
                acc0 += wgt * hv.x; acc1 += wgt * hv.y;
                acc2 += wgt * hv.z; acc3 += wgt * hv.w;
                racc += wgt * rv;
            }
        }
        // reduce across the 4 groups
        acc0 += __shfl_xor(acc0, 16, 64); acc0 += __shfl_xor(acc0, 32, 64);
        acc1 += __shfl_xor(acc1, 16, 64); acc1 += __shfl_xor(acc1, 32, 64);
        acc2 += __shfl_xor(acc2, 16, 64); acc2 += __shfl_xor(acc2, 32, 64);
        acc3 += __shfl_xor(acc3, 16, 64); acc3 += __shfl_xor(acc3, 32, 64);
        racc += __shfl_xor(racc, 16, 64); racc += __shfl_xor(racc, 32, 64);
        s    += __shfl_xor(s, 16, 64);    s    += __shfl_xor(s, 32, 64);
        float inv = (end > base) ? 1.f / s : 0.f;
        if (g == 0) {
            float4 av = { acc0 * inv, acc1 * inv, acc2 * inv, acc3 * inv };
            *(float4*)&arow[w][lg << 2] = av;
            rrow[w][lg] = racc * inv;
        }
        // same-wave LDS stage (pattern verified in R1-R3)
        float mm = 0.f;
#pragma unroll
        for (int d4 = 0; d4 < 16; ++d4) {
            float4 a = *(const float4*)&arow[w][d4 * 4];
            int d = d4 * 4;
            mm += a.x * Wl[(d + 0) * 64 + lane];
            mm += a.y * Wl[(d + 1) * 64 + lane];
            mm += a.z * Wl[(d + 2) * 64 + lane];
            mm += a.w * Wl[(d + 3) * 64 + lane];
        }
#pragma unroll
        for (int t = 0; t < 16; ++t) mm += rrow[w][t] * Ww[t * 64 + lane];
        size_t idx = (size_t)n * 64 + lane;
        float hv = lrelu(h_in[idx] + mm);
        h_out[idx] = hv;
        float x = hv * asj, y = hv * adj;
#pragma unroll
        for (int o = 32; o; o >>= 1) {
            x += __shfl_xor(x, o, 64);
            y += __shfl_xor(y, o, 64);
        }
        if (lane == 0) { hs_out[n] = x; hd_out[n] = y; }
    }
}

// block per graph readout (graph_id sorted -> contiguous ranges via binary search)
__global__ void k_readout(const float* __restrict__ h,
                          const float* __restrict__ d_edge,
                          const int* __restrict__ graph_id,
                          const float* __restrict__ i_node,
                          const float* __restrict__ W_i,
                          const float* __restrict__ w_d,
                          const float* __restrict__ b_d,
                          const float* __restrict__ W_mlp,
                          const float* __restrict__ b_mlp,
                          const float* __restrict__ W_out,
                          const float* __restrict__ b_out,
                          float* __restrict__ out) {
    int g = blockIdx.x, j = threadIdx.x;
    int lo = 0, hi = N_RN;
    while (lo < hi) { int mid = (lo + hi) >> 1; if (graph_id[mid] < g) lo = mid + 1; else hi = mid; }
    int start = lo;
    hi = N_RN;
    while (lo < hi) { int mid = (lo + hi) >> 1; if (graph_id[mid] < g + 1) lo = mid + 1; else hi = mid; }
    int end = lo;

    float wd = w_d[0], bd = b_d[0];
    float acc0 = 0.f, acc1 = 0.f, sg = 0.f;
    for (int n = start; n < end; ++n) {
        float hv = h[(size_t)n * 64 + j];
        float de = d_edge[n];
        float gate = 1.f / (1.f + __expf(-(de * wd + bd)));
        acc0 += hv;
        acc1 += gate * hv;
        sg += gate;
    }
    float hij = i_node[g] * W_i[j] + acc1;
    float pooled = acc0 + sg * hij;

    __shared__ float xa[64], xb[64];
    xa[j] = pooled;
    __syncthreads();
#pragma unroll
    for (int layer = 0; layer < 3; ++layer) {
        const float* W = W_mlp + layer * 4096;
        float* srcb = (layer & 1) ? xb : xa;
        float* dstb = (layer & 1) ? xa : xb;
        float acc = b_mlp[layer * 64 + j];
        for (int d = 0; d < 64; ++d) acc += srcb[d] * W[d * 64 + j];
        acc = fmaxf(acc, 0.f);
        __syncthreads();
        dstb[j] = acc;
        __syncthreads();
    }
    float v = xb[j] * W_out[j];
#pragma unroll
    for (int off = 32; off; off >>= 1) v += __shfl_xor(v, off, 64);
    if (j == 0) out[g] = v + b_out[0];
}

extern "C" void kernel_launch(void* const* d_in, const int* in_sizes, int n_in,
                              void* d_out, int out_size, void* d_ws, size_t ws_size,
                              hipStream_t stream) {
    const float* r_node  = (const float*)d_in[0];
    const float* i_node  = (const float*)d_in[1];
    const float* r_edge  = (const float*)d_in[2];
    const float* d_edge  = (const float*)d_in[3];
    const int*   r2r_src = (const int*)d_in[4];
    const int*   r2r_dst = (const int*)d_in[5];
    const int*   graph_id= (const int*)d_in[6];
    const float* W_r     = (const float*)d_in[7];
    const float* W_i     = (const float*)d_in[8];
    const float* W_e     = (const float*)d_in[9];
    const float* Wm      = (const float*)d_in[10];
    const float* a_s     = (const float*)d_in[11];
    const float* a_d     = (const float*)d_in[12];
    const float* a_e     = (const float*)d_in[13];
    const float* w_d     = (const float*)d_in[14];
    const float* b_d     = (const float*)d_in[15];
    const float* W_mlp   = (const float*)d_in[16];
    const float* b_mlp   = (const float*)d_in[17];
    const float* W_out   = (const float*)d_in[18];
    const float* b_out   = (const float*)d_in[19];
    float* out = (float*)d_out;

    float* ws = (float*)d_ws;
    float* h0   = ws;                                  // N*64
    float* h1   = h0 + (size_t)N_RN * 64;              // N*64
    float* hs0  = h1 + (size_t)N_RN * 64;              // N
    float* hd0  = hs0 + N_RN;                          // N
    float* hs1  = hd0 + N_RN;                          // N
    float* hd1  = hs1 + N_RN;                          // N
    float* WeWm = hd1 + N_RN;                          // 4*16*64
    int*   deg  = (int*)(WeWm + 4096);                 // N
    int*   offs = deg + N_RN;                          // N+1
    int*   cur  = offs + N_RN + 1;                     // N
    int*   bsum = cur + N_RN;                          // 512
    int*   src_perm = bsum + 512;                      // E
    float* r16_perm = (float*)(src_perm + N_ED);       // 16*E

    k_embed_h<<<2048, 256, 0, stream>>>(r_node, W_r, a_s, a_d, h0, hs0, hd0);
    k_wewm<<<16, 256, 0, stream>>>(W_e, Wm, WeWm);

    hipMemsetAsync(deg, 0, N_RN * sizeof(int), stream);
    k_hist<<<(N_ED + 255) / 256, 256, 0, stream>>>(r2r_dst, deg);
    k_scan_a<<<SCAN_NB, SCAN_CH, 0, stream>>>(deg, bsum);
    k_scan_b<<<1, 512, 0, stream>>>(bsum);
    k_scan_c<<<SCAN_NB, SCAN_CH, 0, stream>>>(deg, bsum, offs, cur);
    k_scatter<<<(N_ED + 255) / 256, 256, 0, stream>>>(r_edge, r2r_src, r2r_dst,
                                                      cur, src_perm, r16_perm);

    float* hin = h0;  float* hout = h1;
    float* hsi = hs0; float* hdi = hd0;
    float* hso = hs1; float* hdo = hd1;
    for (int l = 0; l < 4; ++l) {
        int ln = (l + 1) & 3;
        k_layer<<<2048, 256, 0, stream>>>(hin, hsi, hdi, offs, src_perm, r16_perm,
                                          W_e, a_e + l * 64, Wm + l * 4096, WeWm + l * 1024,
                                          a_s + ln * 64, a_d + ln * 64,
                                          hout, hso, hdo);
        float* t;
        t = hin; hin = hout; hout = t;
        t = hsi; hsi = hso; hso = t;
        t = hdi; hdi = hdo; hdo = t;
    }

    k_readout<<<N_G, 64, 0, stream>>>(hin, d_edge, graph_id, i_node, W_i, w_d, b_d,
                                      W_mlp, b_mlp, W_out, b_out, out);
}